// Round 1
// baseline (400.577 us; speedup 1.0000x reference)
//
#include <hip/hip_runtime.h>

// entmax-1.5 over last axis of (1024, 255, 512) fp32.
// Sort-free: Newton solve for tau s.t. sum(relu(x - tau)^2) == 1,
// which is exactly the threshold the reference's sorted-scan computes.
// One 64-lane wave per row; 8 elems/lane in registers.

constexpr int N_FEAT = 512;
constexpr long long N_ROWS = 1024LL * 255LL;   // 261120
constexpr int ROWS_PER_BLOCK = 4;              // 256 threads = 4 waves

__global__ __launch_bounds__(256) void entmax15_kernel(const float* __restrict__ in,
                                                       float* __restrict__ out) {
    const int  wave = threadIdx.x >> 6;
    const int  lane = threadIdx.x & 63;
    const long long row = (long long)blockIdx.x * ROWS_PER_BLOCK + wave;

    const float* rp = in  + row * N_FEAT;
    float*       op = out + row * N_FEAT;

    // coalesced: lane i reads float4 #i and #(64+i) of the row
    const float4 v0 = reinterpret_cast<const float4*>(rp)[lane];
    const float4 v1 = reinterpret_cast<const float4*>(rp)[64 + lane];
    float x[8] = {v0.x, v0.y, v0.z, v0.w, v1.x, v1.y, v1.z, v1.w};
#pragma unroll
    for (int i = 0; i < 8; ++i) x[i] *= 0.5f;   // logits / 2

    // row max (per-lane tree + 6-step wave butterfly)
    float m = fmaxf(fmaxf(fmaxf(x[0], x[1]), fmaxf(x[2], x[3])),
                    fmaxf(fmaxf(x[4], x[5]), fmaxf(x[6], x[7])));
#pragma unroll
    for (int off = 32; off >= 1; off >>= 1)
        m = fmaxf(m, __shfl_xor(m, off, 64));
#pragma unroll
    for (int i = 0; i < 8; ++i) x[i] -= m;      // now max(x) == 0, tau* in [-1, 0]

    // Newton: f(tau) = sum relu(x - tau)^2, convex decreasing; solve f = 1.
    // tau0 = -1 <= tau*; iterates approach tau* from below -> s1 >= 1 always.
    float tau = -1.0f;
#pragma unroll
    for (int it = 0; it < 12; ++it) {
        float s1 = 0.0f, s2 = 0.0f;
#pragma unroll
        for (int i = 0; i < 8; ++i) {
            float d = fmaxf(x[i] - tau, 0.0f);
            s1 += d;
            s2 = fmaf(d, d, s2);
        }
#pragma unroll
        for (int off = 32; off >= 1; off >>= 1) {
            s1 += __shfl_xor(s1, off, 64);
            s2 += __shfl_xor(s2, off, 64);
        }
        tau += (s2 - 1.0f) / fmaxf(2.0f * s1, 1e-12f);
    }

    // out = relu(x - tau)^2, coalesced float4 stores
    float4 o0, o1;
    float d;
    d = fmaxf(x[0] - tau, 0.0f); o0.x = d * d;
    d = fmaxf(x[1] - tau, 0.0f); o0.y = d * d;
    d = fmaxf(x[2] - tau, 0.0f); o0.z = d * d;
    d = fmaxf(x[3] - tau, 0.0f); o0.w = d * d;
    d = fmaxf(x[4] - tau, 0.0f); o1.x = d * d;
    d = fmaxf(x[5] - tau, 0.0f); o1.y = d * d;
    d = fmaxf(x[6] - tau, 0.0f); o1.z = d * d;
    d = fmaxf(x[7] - tau, 0.0f); o1.w = d * d;
    reinterpret_cast<float4*>(op)[lane]      = o0;
    reinterpret_cast<float4*>(op)[64 + lane] = o1;
}

extern "C" void kernel_launch(void* const* d_in, const int* in_sizes, int n_in,
                              void* d_out, int out_size, void* d_ws, size_t ws_size,
                              hipStream_t stream) {
    const float* in  = (const float*)d_in[0];
    float*       out = (float*)d_out;
    const unsigned nblocks = (unsigned)(N_ROWS / ROWS_PER_BLOCK);  // 65280
    entmax15_kernel<<<dim3(nblocks), dim3(256), 0, stream>>>(in, out);
}

// Round 2
// 211.816 us; speedup vs baseline: 1.8912x; 1.8912x over previous
//
#include <hip/hip_runtime.h>

// entmax-1.5 over last axis of (1024, 255, 512) fp32.
// Newton solve for tau s.t. sum(relu(x - tau)^2) == 1 (sort-free).
// Layout: 16 lanes per row, 4 rows per wave, 32 elems/lane in registers.
// Cross-lane reductions via 4-step DPP butterfly within each 16-lane group
// (quad_perm xor1, xor2, row_half_mirror, row_mirror) -- one VALU op per
// step, serves all 4 rows of the wave simultaneously, no DS traffic.

constexpr int N_FEAT = 512;
constexpr long long N_ROWS = 1024LL * 255LL;   // 261120
constexpr int ROWS_PER_BLOCK = 16;             // 256 threads = 4 waves x 4 rows

// DPP ctrl encodings (GCN/CDNA): quad_perm xor1 = 0xB1, quad_perm xor2 = 0x4E,
// ROW_HALF_MIRROR = 0x141 (i -> 7-i within 8), ROW_MIRROR = 0x140 (i -> 15-i).
// Sequence of the four = full 16-lane reduction, result in every lane.
template <int CTRL>
__device__ __forceinline__ float dpp_add(float v) {
    int p = __builtin_amdgcn_update_dpp(0, __float_as_int(v), CTRL, 0xF, 0xF, true);
    return v + __int_as_float(p);
}
template <int CTRL>
__device__ __forceinline__ float dpp_max(float v) {
    int p = __builtin_amdgcn_update_dpp(0, __float_as_int(v), CTRL, 0xF, 0xF, true);
    return fmaxf(v, __int_as_float(p));
}

__device__ __forceinline__ float reduce16_add(float v) {
    v = dpp_add<0xB1>(v);   // xor 1 (quad_perm [1,0,3,2])
    v = dpp_add<0x4E>(v);   // xor 2 (quad_perm [2,3,0,1])
    v = dpp_add<0x141>(v);  // row_half_mirror: pairs across quads within 8
    v = dpp_add<0x140>(v);  // row_mirror: pairs across 8-halves within 16
    return v;
}
__device__ __forceinline__ float reduce16_max(float v) {
    v = dpp_max<0xB1>(v);
    v = dpp_max<0x4E>(v);
    v = dpp_max<0x141>(v);
    v = dpp_max<0x140>(v);
    return v;
}

__global__ __launch_bounds__(256) void entmax15_kernel(const float* __restrict__ in,
                                                       float* __restrict__ out) {
    const int wave = threadIdx.x >> 6;
    const int lane = threadIdx.x & 63;
    const int g    = lane >> 4;   // row index within wave (0..3)
    const int t    = lane & 15;   // lane within the row's 16-lane group

    const long long row = (long long)blockIdx.x * ROWS_PER_BLOCK + wave * 4 + g;
    const float* rp = in  + row * N_FEAT + t * 4;
    float*       op = out + row * N_FEAT + t * 4;

    // lane holds 8 float4s of its row: positions t*4 + k*64, k = 0..7
    float4 x[8];
#pragma unroll
    for (int k = 0; k < 8; ++k)
        x[k] = *reinterpret_cast<const float4*>(rp + k * 64);

    // row max of raw logits (per-lane tree + 16-lane DPP reduce)
    float m = fmaxf(fmaxf(x[0].x, x[0].y), fmaxf(x[0].z, x[0].w));
#pragma unroll
    for (int k = 1; k < 8; ++k)
        m = fmaxf(m, fmaxf(fmaxf(x[k].x, x[k].y), fmaxf(x[k].z, x[k].w)));
    m = reduce16_max(m);
    m *= 0.5f;   // max of logits/2 (exact: *0.5 commutes with max)

    // x = logits*0.5 - m   (single fma pass; max(x) == 0 exactly)
#pragma unroll
    for (int k = 0; k < 8; ++k) {
        x[k].x = fmaf(x[k].x, 0.5f, -m);
        x[k].y = fmaf(x[k].y, 0.5f, -m);
        x[k].z = fmaf(x[k].z, 0.5f, -m);
        x[k].w = fmaf(x[k].w, 0.5f, -m);
    }

    // Newton on f(tau) = sum relu(x-tau)^2 = 1; convex decreasing,
    // tau0 = -1 <= tau*, iterates increase monotonically -> s1 >= 1.
    float tau = -1.0f;
#pragma unroll
    for (int it = 0; it < 10; ++it) {
        float s1 = 0.0f, s2 = 0.0f;
#pragma unroll
        for (int k = 0; k < 8; ++k) {
            float d;
            d = fmaxf(x[k].x - tau, 0.0f); s1 += d; s2 = fmaf(d, d, s2);
            d = fmaxf(x[k].y - tau, 0.0f); s1 += d; s2 = fmaf(d, d, s2);
            d = fmaxf(x[k].z - tau, 0.0f); s1 += d; s2 = fmaf(d, d, s2);
            d = fmaxf(x[k].w - tau, 0.0f); s1 += d; s2 = fmaf(d, d, s2);
        }
        s1 = reduce16_add(s1);
        s2 = reduce16_add(s2);
        tau += (s2 - 1.0f) / fmaxf(2.0f * s1, 1e-12f);
    }

    // out = relu(x - tau)^2
#pragma unroll
    for (int k = 0; k < 8; ++k) {
        float4 o;
        float d;
        d = fmaxf(x[k].x - tau, 0.0f); o.x = d * d;
        d = fmaxf(x[k].y - tau, 0.0f); o.y = d * d;
        d = fmaxf(x[k].z - tau, 0.0f); o.z = d * d;
        d = fmaxf(x[k].w - tau, 0.0f); o.w = d * d;
        *reinterpret_cast<float4*>(op + k * 64) = o;
    }
}

extern "C" void kernel_launch(void* const* d_in, const int* in_sizes, int n_in,
                              void* d_out, int out_size, void* d_ws, size_t ws_size,
                              hipStream_t stream) {
    const float* in  = (const float*)d_in[0];
    float*       out = (float*)d_out;
    const unsigned nblocks = (unsigned)(N_ROWS / ROWS_PER_BLOCK);  // 16320
    entmax15_kernel<<<dim3(nblocks), dim3(256), 0, stream>>>(in, out);
}

// Round 3
// 209.685 us; speedup vs baseline: 1.9104x; 1.0102x over previous
//
#include <hip/hip_runtime.h>

// entmax-1.5 over last axis of (1024, 255, 512) fp32.
// tau solve: 1 Michelot quadratic step (exact on current support) + 6 Newton.
// Layout: 16 lanes/row, 4 rows/wave, 32 elems/lane held as v2f pairs so the
// backend can select packed fp32 (v_pk_add/max/fma_f32). Reductions via
// 4-step DPP butterfly within each 16-lane group.

typedef float v2f __attribute__((ext_vector_type(2)));

constexpr int N_FEAT = 512;
constexpr long long N_ROWS = 1024LL * 255LL;   // 261120
constexpr int ROWS_PER_BLOCK = 16;             // 256 threads = 4 waves x 4 rows
constexpr float TAU_HI = -0.044194174f;        // -1/sqrt(512): tau* <= this always

template <int CTRL>
__device__ __forceinline__ float dpp_add(float v) {
    int p = __builtin_amdgcn_update_dpp(0, __float_as_int(v), CTRL, 0xF, 0xF, true);
    return v + __int_as_float(p);
}
template <int CTRL>
__device__ __forceinline__ float dpp_max(float v) {
    int p = __builtin_amdgcn_update_dpp(0, __float_as_int(v), CTRL, 0xF, 0xF, true);
    return fmaxf(v, __int_as_float(p));
}
__device__ __forceinline__ float reduce16_add(float v) {
    v = dpp_add<0xB1>(v);   // quad_perm xor1
    v = dpp_add<0x4E>(v);   // quad_perm xor2
    v = dpp_add<0x141>(v);  // row_half_mirror
    v = dpp_add<0x140>(v);  // row_mirror
    return v;
}
__device__ __forceinline__ float reduce16_max(float v) {
    v = dpp_max<0xB1>(v);
    v = dpp_max<0x4E>(v);
    v = dpp_max<0x141>(v);
    v = dpp_max<0x140>(v);
    return v;
}

__global__ __launch_bounds__(256) void entmax15_kernel(const float* __restrict__ in,
                                                       float* __restrict__ out) {
    const int wave = threadIdx.x >> 6;
    const int lane = threadIdx.x & 63;
    const int g    = lane >> 4;   // row within wave (0..3)
    const int t    = lane & 15;   // lane within 16-lane row group

    const long long row = (long long)blockIdx.x * ROWS_PER_BLOCK + wave * 4 + g;
    const float* rp = in  + row * N_FEAT + t * 4;
    float*       op = out + row * N_FEAT + t * 4;

    // coalesced float4 loads: positions t*4 + k*64
    float4 v[8];
#pragma unroll
    for (int k = 0; k < 8; ++k)
        v[k] = *reinterpret_cast<const float4*>(rp + k * 64);

    // row max of raw logits, then scale (max(x/2) = max(x)/2 exactly)
    float m = fmaxf(fmaxf(v[0].x, v[0].y), fmaxf(v[0].z, v[0].w));
#pragma unroll
    for (int k = 1; k < 8; ++k)
        m = fmaxf(m, fmaxf(fmaxf(v[k].x, v[k].y), fmaxf(v[k].z, v[k].w)));
    m = reduce16_max(m) * 0.5f;

    // x = logits*0.5 - m, stored as packed pairs; max(x) == 0, tau* in [-1, TAU_HI]
    v2f x2[16];
#pragma unroll
    for (int k = 0; k < 8; ++k) {
        x2[2 * k]     = (v2f){fmaf(v[k].x, 0.5f, -m), fmaf(v[k].y, 0.5f, -m)};
        x2[2 * k + 1] = (v2f){fmaf(v[k].z, 0.5f, -m), fmaf(v[k].w, 0.5f, -m)};
    }

    const v2f zero2 = {0.0f, 0.0f};
    const v2f one2  = {1.0f, 1.0f};

    // --- iter 0: Michelot quadratic solve at tau = -1 ---
    // On support A = {x > tau}: k*d^2 - 2*s1*d + (s2-1) = 0, take smaller root.
    // Exact whenever the support is already correct; lands at-or-above tau*.
    v2f s1v = zero2, s2v = zero2, kvv = zero2;
#pragma unroll
    for (int k = 0; k < 16; ++k) {
        v2f d = __builtin_elementwise_max(x2[k] + one2, zero2);
        s1v += d;
        s2v += d * d;
        kvv.x += (d.x > 0.0f) ? 1.0f : 0.0f;
        kvv.y += (d.y > 0.0f) ? 1.0f : 0.0f;
    }
    float s1 = reduce16_add(s1v.x + s1v.y);
    float s2 = reduce16_add(s2v.x + s2v.y);
    float kk = reduce16_add(kvv.x + kvv.y);
    float disc = fmaxf(fmaf(s1, s1, -kk * (s2 - 1.0f)), 0.0f);
    float tau = -1.0f + (s1 - __builtin_amdgcn_sqrtf(disc)) * __builtin_amdgcn_rcpf(kk);
    tau = fminf(fmaxf(tau, -1.0f), TAU_HI);

    // --- Newton polish: f(tau) = sum relu(x-tau)^2 = 1 ---
    // One step from above returns below tau*; then monotone quadratic from below.
    // Clamp keeps s1 >= -TAU_HI so the rcp is always safe.
#pragma unroll
    for (int it = 0; it < 6; ++it) {
        v2f t2 = {tau, tau};
        v2f a = zero2, b = zero2;
#pragma unroll
        for (int k = 0; k < 16; ++k) {
            v2f d = __builtin_elementwise_max(x2[k] - t2, zero2);
            a += d;
            b += d * d;
        }
        float S1 = reduce16_add(a.x + a.y);
        float S2 = reduce16_add(b.x + b.y);
        tau += (S2 - 1.0f) * __builtin_amdgcn_rcpf(2.0f * S1);
        tau = fminf(fmaxf(tau, -1.0f), TAU_HI);
    }

    // out = relu(x - tau)^2, coalesced float4 stores
    v2f t2 = {tau, tau};
#pragma unroll
    for (int k = 0; k < 8; ++k) {
        v2f d0 = __builtin_elementwise_max(x2[2 * k]     - t2, zero2);
        v2f d1 = __builtin_elementwise_max(x2[2 * k + 1] - t2, zero2);
        d0 *= d0;
        d1 *= d1;
        float4 o = {d0.x, d0.y, d1.x, d1.y};
        *reinterpret_cast<float4*>(op + k * 64) = o;
    }
}

extern "C" void kernel_launch(void* const* d_in, const int* in_sizes, int n_in,
                              void* d_out, int out_size, void* d_ws, size_t ws_size,
                              hipStream_t stream) {
    const float* in  = (const float*)d_in[0];
    float*       out = (float*)d_out;
    const unsigned nblocks = (unsigned)(N_ROWS / ROWS_PER_BLOCK);  // 16320
    entmax15_kernel<<<dim3(nblocks), dim3(256), 0, stream>>>(in, out);
}

// Round 5
// 200.954 us; speedup vs baseline: 1.9934x; 1.0434x over previous
//
#include <hip/hip_runtime.h>

// entmax-1.5 over last axis of (1024, 255, 512) fp32.
// tau solve: 1 Michelot quadratic step + 6 Newton (sort-free).
// Layout: 16 lanes/row, 4 rows/wave, 32 elems/lane as v2f pairs (packed fp32).
// R5: = R4 with ext_vector float4 (clang-native) so nontemporal_store compiles.

typedef float v2f __attribute__((ext_vector_type(2)));
typedef float v4f __attribute__((ext_vector_type(4)));

constexpr int N_FEAT = 512;
constexpr long long N_ROWS = 1024LL * 255LL;   // 261120
constexpr int ROWS_PER_BLOCK = 16;             // 256 threads = 4 waves x 4 rows
constexpr float TAU_HI = -0.044194174f;        // -1/sqrt(512) >= tau* always

template <int CTRL>
__device__ __forceinline__ float dpp_add(float v) {
    int p = __builtin_amdgcn_update_dpp(0, __float_as_int(v), CTRL, 0xF, 0xF, true);
    return v + __int_as_float(p);
}
template <int CTRL>
__device__ __forceinline__ float dpp_max(float v) {
    int p = __builtin_amdgcn_update_dpp(0, __float_as_int(v), CTRL, 0xF, 0xF, true);
    return fmaxf(v, __int_as_float(p));
}
__device__ __forceinline__ float reduce16_add(float v) {
    v = dpp_add<0xB1>(v);   // quad_perm xor1
    v = dpp_add<0x4E>(v);   // quad_perm xor2
    v = dpp_add<0x141>(v);  // row_half_mirror
    v = dpp_add<0x140>(v);  // row_mirror
    return v;
}
__device__ __forceinline__ float reduce16_max(float v) {
    v = dpp_max<0xB1>(v);
    v = dpp_max<0x4E>(v);
    v = dpp_max<0x141>(v);
    v = dpp_max<0x140>(v);
    return v;
}

__global__ __launch_bounds__(256, 8) void entmax15_kernel(const float* __restrict__ in,
                                                          float* __restrict__ out) {
    const int wave = threadIdx.x >> 6;
    const int lane = threadIdx.x & 63;
    const int g    = lane >> 4;   // row within wave (0..3)
    const int t    = lane & 15;   // lane within 16-lane row group

    const long long row = (long long)blockIdx.x * ROWS_PER_BLOCK + wave * 4 + g;
    const float* rp = in  + row * N_FEAT + t * 4;
    float*       op = out + row * N_FEAT + t * 4;

    // Stream coalesced float4 loads straight into x2 (scaled by 0.5 on the fly).
    v2f x2[16];
#pragma unroll
    for (int k = 0; k < 8; ++k) {
        v4f v = *reinterpret_cast<const v4f*>(rp + k * 64);
        x2[2 * k]     = (v2f){v.x, v.y} * 0.5f;
        x2[2 * k + 1] = (v2f){v.z, v.w} * 0.5f;
    }

    // row max (packed tree + 16-lane DPP reduce)
    v2f mm = x2[0];
#pragma unroll
    for (int k = 1; k < 16; ++k) mm = __builtin_elementwise_max(mm, x2[k]);
    float m = reduce16_max(fmaxf(mm.x, mm.y));

    // x -= m; now max(x) == 0, tau* in [-1, TAU_HI]
    const v2f m2 = {m, m};
#pragma unroll
    for (int k = 0; k < 16; ++k) x2[k] -= m2;

    const v2f zero2 = {0.0f, 0.0f};
    const v2f one2  = {1.0f, 1.0f};

    // --- iter 0: Michelot quadratic solve at tau = -1 ---
    // On support A = {x > tau}: |A|*d^2 - 2*s1*d + (s2-1) = 0, smaller root.
    v2f s1v = zero2, s2v = zero2, kvv = zero2;
#pragma unroll
    for (int k = 0; k < 16; ++k) {
        v2f d = __builtin_elementwise_max(x2[k] + one2, zero2);
        s1v += d;
        s2v += d * d;
        kvv.x += (d.x > 0.0f) ? 1.0f : 0.0f;
        kvv.y += (d.y > 0.0f) ? 1.0f : 0.0f;
    }
    float s1 = reduce16_add(s1v.x + s1v.y);
    float s2 = reduce16_add(s2v.x + s2v.y);
    float kk = reduce16_add(kvv.x + kvv.y);
    float disc = fmaxf(fmaf(s1, s1, -kk * (s2 - 1.0f)), 0.0f);
    float tau = -1.0f + (s1 - __builtin_amdgcn_sqrtf(disc)) * __builtin_amdgcn_rcpf(kk);
    tau = fminf(fmaxf(tau, -1.0f), TAU_HI);

    // --- Newton polish: f(tau) = sum relu(x-tau)^2 = 1 ---
#pragma unroll
    for (int it = 0; it < 6; ++it) {
        v2f t2 = {tau, tau};
        v2f a = zero2, b = zero2;
#pragma unroll
        for (int k = 0; k < 16; ++k) {
            v2f d = __builtin_elementwise_max(x2[k] - t2, zero2);
            a += d;
            b += d * d;
        }
        float S1 = reduce16_add(a.x + a.y);
        float S2 = reduce16_add(b.x + b.y);
        tau += (S2 - 1.0f) * __builtin_amdgcn_rcpf(2.0f * S1);
        tau = fminf(fmaxf(tau, -1.0f), TAU_HI);
    }

    // out = relu(x - tau)^2, nontemporal ext-vector stores (output never re-read)
    v2f t2 = {tau, tau};
#pragma unroll
    for (int k = 0; k < 8; ++k) {
        v2f d0 = __builtin_elementwise_max(x2[2 * k]     - t2, zero2);
        v2f d1 = __builtin_elementwise_max(x2[2 * k + 1] - t2, zero2);
        d0 *= d0;
        d1 *= d1;
        v4f o = {d0.x, d0.y, d1.x, d1.y};
        __builtin_nontemporal_store(o, reinterpret_cast<v4f*>(op + k * 64));
    }
}

extern "C" void kernel_launch(void* const* d_in, const int* in_sizes, int n_in,
                              void* d_out, int out_size, void* d_ws, size_t ws_size,
                              hipStream_t stream) {
    const float* in  = (const float*)d_in[0];
    float*       out = (float*)d_out;
    const unsigned nblocks = (unsigned)(N_ROWS / ROWS_PER_BLOCK);  // 16320
    entmax15_kernel<<<dim3(nblocks), dim3(256), 0, stream>>>(in, out);
}